// Round 7
// baseline (291.126 us; speedup 1.0000x reference)
//
#include <hip/hip_runtime.h>
#include <hip/hip_bf16.h>

#define D_MODEL 1024
#define NUM_HEADS 16
#define D_K 64
#define BATCH 2
#define SEQ 2048

typedef __attribute__((ext_vector_type(8))) short bf16x8;
typedef __attribute__((ext_vector_type(4))) float f32x4;

union P16 { int4 i4; ushort u[8]; };

__device__ __forceinline__ float bf2f(ushort u) {
    union { unsigned int i; float f; } c; c.i = ((unsigned int)u) << 16; return c.f;
}
__device__ __forceinline__ ushort f2bf(float f) {
    union { float f; unsigned int i; } c; c.f = f;
    unsigned int x = c.i;
    return (ushort)((x + 0x7fff + ((x >> 16) & 1)) >> 16);
}

// async 16B global->LDS (DMA; dest = wave-uniform base + lane*16)
typedef __attribute__((address_space(1))) void gv_t;
typedef __attribute__((address_space(3))) void lv_t;
__device__ __forceinline__ void gll16(const ushort* g, ushort* l) {
    __builtin_amdgcn_global_load_lds((gv_t*)g, (lv_t*)l, 16, 0, 0);
}

// Decide whether float inputs are fp32 (flag=1) or bf16 (flag=0) from x's bits.
__global__ void detect_f32(const ushort* __restrict__ x, int* __restrict__ flag) {
    int lane = threadIdx.x;               // 64 threads
    ushort u = x[2 * lane];
    int e = (u >> 7) & 0xFF;
    bool plausible = (e >= 100 && e <= 141);
    unsigned long long b = __ballot(plausible);
    if (lane == 0) flag[0] = (__popcll(b) < 32) ? 1 : 0;
}

// src (fp32 or bf16 per flag) -> dst bf16, 8 elems/thread
__global__ void convert_bf16(const void* __restrict__ src, ushort* __restrict__ dst,
                             int n, const int* __restrict__ flag) {
    int i = (blockIdx.x * 256 + threadIdx.x) * 8;
    if (i >= n) return;
    if (*flag) {
        const float* f = (const float*)src + i;
        float4 a = *(const float4*)f, b = *(const float4*)(f + 4);
        P16 r;
        r.u[0] = f2bf(a.x); r.u[1] = f2bf(a.y); r.u[2] = f2bf(a.z); r.u[3] = f2bf(a.w);
        r.u[4] = f2bf(b.x); r.u[5] = f2bf(b.y); r.u[6] = f2bf(b.z); r.u[7] = f2bf(b.w);
        *(int4*)(dst + i) = r.i4;
    } else {
        *(int4*)(dst + i) = *(const int4*)((const ushort*)src + i);
    }
}

// WT[n][k] = W[k][n], bf16 out. 64x64 tiles, 256 threads.
__global__ void transpose_w(const void* __restrict__ W, ushort* __restrict__ WT,
                            int K, int N, const int* __restrict__ flag) {
    __shared__ ushort t[64][72];
    const int tx = threadIdx.x;
    const int n0 = blockIdx.x * 64, k0 = blockIdx.y * 64;
    const bool f32 = (*flag) != 0;
    #pragma unroll
    for (int p = 0; p < 16; ++p) {
        int r = p * 4 + (tx >> 6), c = tx & 63;
        float v = f32 ? ((const float*)W)[(size_t)(k0 + r) * N + n0 + c]
                      : bf2f(((const ushort*)W)[(size_t)(k0 + r) * N + n0 + c]);
        t[r][c] = f2bf(v);
    }
    __syncthreads();
    #pragma unroll
    for (int p = 0; p < 16; ++p) {
        int nn = p * 4 + (tx >> 6), kk = tx & 63;
        WT[(size_t)(n0 + nn) * K + k0 + kk] = t[kk][nn];
    }
}

// ---------------- m97-style GEMM (unchanged, verified round 5) ----------------
template<int MODE>
__global__ __launch_bounds__(256)
void gemm128(const ushort* __restrict__ A, const ushort* __restrict__ WT,
             const ushort* __restrict__ bias, void* __restrict__ out,
             int N, int K, const int* __restrict__ flag)
{
    __shared__ ushort As[128 * 32];
    __shared__ ushort Bs[128 * 32];

    const int tid = threadIdx.x;
    const int w = tid >> 6, lane = tid & 63;
    const int ln = lane & 15, quad = lane >> 4;
    const int m0 = blockIdx.y * 128, n0 = blockIdx.x * 128;
    const int wm = (w >> 1) * 64, wn = (w & 1) * 64;

    const int s0 = w * 128 + lane, s1 = s0 + 64;
    const int ar0 = s0 >> 2, ak0 = ((s0 & 3) ^ ((ar0 >> 1) & 3)) * 8;
    const int ar1 = s1 >> 2, ak1 = ((s1 & 3) ^ ((ar1 >> 1) & 3)) * 8;
    const size_t aoff0 = (size_t)(m0 + ar0) * K + ak0;
    const size_t aoff1 = (size_t)(m0 + ar1) * K + ak1;
    const size_t boff0 = (size_t)(n0 + ar0) * K + ak0;
    const size_t boff1 = (size_t)(n0 + ar1) * K + ak1;
    ushort* asd0 = As + (size_t)(w * 2)     * 512;
    ushort* asd1 = As + (size_t)(w * 2 + 1) * 512;
    ushort* bsd0 = Bs + (size_t)(w * 2)     * 512;
    ushort* bsd1 = Bs + (size_t)(w * 2 + 1) * 512;

    const int physc = (quad ^ ((ln >> 1) & 3)) * 8;

    f32x4 acc[4][4] = {};

    for (int k0c = 0; k0c < K; k0c += 32) {
        __syncthreads();
        gll16(A  + aoff0 + k0c, asd0);
        gll16(A  + aoff1 + k0c, asd1);
        gll16(WT + boff0 + k0c, bsd0);
        gll16(WT + boff1 + k0c, bsd1);
        __syncthreads();

        bf16x8 af[4], bf[4];
        #pragma unroll
        for (int t = 0; t < 4; ++t) {
            af[t] = *(const bf16x8*)(As + (wm + t * 16 + ln) * 32 + physc);
            bf[t] = *(const bf16x8*)(Bs + (wn + t * 16 + ln) * 32 + physc);
        }
        #pragma unroll
        for (int mi = 0; mi < 4; ++mi)
            #pragma unroll
            for (int ni = 0; ni < 4; ++ni)
                acc[mi][ni] = __builtin_amdgcn_mfma_f32_16x16x32_bf16(
                    af[mi], bf[ni], acc[mi][ni], 0, 0, 0);
    }

    const int fmode = (MODE == 0) ? *flag : 0;
    #pragma unroll
    for (int mi = 0; mi < 4; ++mi) {
        #pragma unroll
        for (int ni = 0; ni < 4; ++ni) {
            int col = n0 + wn + ni * 16 + ln;
            float bb = bf2f(bias[col]);
            #pragma unroll
            for (int r = 0; r < 4; ++r) {
                int row = m0 + wm + mi * 16 + quad * 4 + r;
                float v = acc[mi][ni][r] + bb;
                if (MODE == 0) {
                    if (fmode) ((float*)out)[(size_t)row * N + col] = v;
                    else       ((ushort*)out)[(size_t)row * N + col] = f2bf(v);
                } else {
                    int which = col >> 10;
                    int h     = (col >> 6) & (NUM_HEADS - 1);
                    int dk    = col & (D_K - 1);
                    int b     = row >> 11;
                    int s     = row & (SEQ - 1);
                    ((ushort*)out)[((((size_t)which * BATCH + b) * NUM_HEADS + h) * SEQ + s) * D_K + dk] = f2bf(v);
                }
            }
        }
    }
}

// ---------------- MFMA flash attention v2 (staging coverage fixed) ----------------
// Block = 2 waves x 64 q-rows (wave owns 32 q = 2 m-tiles, qfrags in regs).
// Round-6 bug: Q/K staging with 128 threads wrote only cols [c, c+16) of each
// 32-col half-row -> cols 16-31/48-63 stale. Fixed: 4 int4 per thread.
__global__ __launch_bounds__(128)
void flash_attn2(const ushort* __restrict__ Q, const ushort* __restrict__ K,
                 const ushort* __restrict__ V, ushort* __restrict__ attn)
{
    __shared__ ushort Ks[64][72];
    __shared__ ushort Vs[64][72];
    __shared__ ushort QPs[64][72];

    const int tid  = threadIdx.x;          // 128 threads, 2 waves
    const int wave = tid >> 6, lane = tid & 63;
    const int ln   = lane & 15, quad = lane >> 4;
    const int bh   = blockIdx.y;
    int qt = blockIdx.x;
    qt = (qt & 1) ? (31 - (qt >> 1)) : (qt >> 1);   // pair light+heavy q-tiles
    const int q0 = qt * 64;
    const size_t base = (size_t)bh * SEQ * D_K;

    // stage Q scaled by 0.125*log2(e); thread owns full 32-col half-row
    {
        const int r = tid >> 1, c = (tid & 1) * 32;
        const ushort* src = Q + base + (size_t)(q0 + r) * D_K + c;
        #pragma unroll
        for (int h = 0; h < 4; ++h) {
            P16 v; v.i4 = *(const int4*)(src + h * 8);
            #pragma unroll
            for (int e = 0; e < 8; ++e) v.u[e] = f2bf(bf2f(v.u[e]) * 0.18033688011f);
            *(int4*)(&QPs[r][c + h * 8]) = v.i4;
        }
    }
    __syncthreads();
    bf16x8 qf[2][2];
    #pragma unroll
    for (int mt = 0; mt < 2; ++mt)
        #pragma unroll
        for (int s = 0; s < 2; ++s)
            qf[mt][s] = *(const bf16x8*)(&QPs[wave * 32 + mt * 16 + ln][s * 32 + quad * 8]);
    // QPs rows [wave*32, +32) are only rewritten (as P) by this same wave.

    f32x4 acc_o[2][4] = {};
    f32x4 acc_l[2] = {};
    float m_r[2][4];
    #pragma unroll
    for (int mt = 0; mt < 2; ++mt)
        #pragma unroll
        for (int r = 0; r < 4; ++r) m_r[mt][r] = -1e30f;

    bf16x8 ones8;
    #pragma unroll
    for (int e = 0; e < 8; ++e) ones8[e] = (short)0x3F80;   // bf16 1.0

    const int ntiles = qt + 1;
    for (int jt = 0; jt < ntiles; ++jt) {
        const int j0 = jt * 64;
        __syncthreads();   // prior iteration's Ks/Vs frag reads complete

        // stage K tile [kv][dk]: full 32-col half-row per thread
        {
            const int r = tid >> 1, c = (tid & 1) * 32;
            const ushort* src = K + base + (size_t)(j0 + r) * D_K + c;
            *(int4*)(&Ks[r][c])      = *(const int4*)(src);
            *(int4*)(&Ks[r][c + 8])  = *(const int4*)(src + 8);
            *(int4*)(&Ks[r][c + 16]) = *(const int4*)(src + 16);
            *(int4*)(&Ks[r][c + 24]) = *(const int4*)(src + 24);
        }
        // stage V transposed [dk][kv]: kv-pair packed b32 writes
        {
            const int p = tid & 31;
            #pragma unroll
            for (int h = 0; h < 2; ++h) {
                const int dk0 = (tid >> 5) * 8 + h * 32;
                P16 v0, v1;
                v0.i4 = *(const int4*)(V + base + (size_t)(j0 + 2 * p)     * D_K + dk0);
                v1.i4 = *(const int4*)(V + base + (size_t)(j0 + 2 * p + 1) * D_K + dk0);
                #pragma unroll
                for (int e = 0; e < 8; ++e) {
                    unsigned int pack = (unsigned int)v0.u[e] | ((unsigned int)v1.u[e] << 16);
                    *(unsigned int*)(&Vs[dk0 + e][2 * p]) = pack;
                }
            }
        }
        __syncthreads();

        // S = Q K^T : 32 q-rows x 64 kv (K-frags read once, shared across mt)
        f32x4 sa[2][4];
        #pragma unroll
        for (int t = 0; t < 4; ++t) {
            bf16x8 k0 = *(const bf16x8*)(&Ks[t * 16 + ln][quad * 8]);
            bf16x8 k1 = *(const bf16x8*)(&Ks[t * 16 + ln][32 + quad * 8]);
            #pragma unroll
            for (int mt = 0; mt < 2; ++mt) {
                f32x4 z = {};
                z = __builtin_amdgcn_mfma_f32_16x16x32_bf16(qf[mt][0], k0, z, 0, 0, 0);
                z = __builtin_amdgcn_mfma_f32_16x16x32_bf16(qf[mt][1], k1, z, 0, 0, 0);
                sa[mt][t] = z;
            }
        }

        // causal mask (last tile only: j0 = q0 there, covers all block rows)
        if (jt == ntiles - 1) {
            #pragma unroll
            for (int mt = 0; mt < 2; ++mt) {
                const int rowb = q0 + wave * 32 + mt * 16 + quad * 4;
                #pragma unroll
                for (int t = 0; t < 4; ++t)
                    #pragma unroll
                    for (int r = 0; r < 4; ++r)
                        if (j0 + t * 16 + ln > rowb + r) sa[mt][t][r] = -1e30f;
            }
        }

        // online softmax, log2 domain. P -> QPs, physcol = col ^ (quad*8)
        #pragma unroll
        for (int mt = 0; mt < 2; ++mt) {
            float alpha[4];
            #pragma unroll
            for (int r = 0; r < 4; ++r) {
                float mx = fmaxf(fmaxf(sa[mt][0][r], sa[mt][1][r]),
                                 fmaxf(sa[mt][2][r], sa[mt][3][r]));
                #pragma unroll
                for (int off = 8; off >= 1; off >>= 1)
                    mx = fmaxf(mx, __shfl_xor(mx, off, 64));
                float mn = fmaxf(m_r[mt][r], mx);
                alpha[r] = exp2f(m_r[mt][r] - mn);
                m_r[mt][r] = mn;
                const int prow = wave * 32 + mt * 16 + quad * 4 + r;
                const int lnx  = ln ^ ((quad & 1) * 8);
                #pragma unroll
                for (int t = 0; t < 4; ++t) {
                    float pe = exp2f(sa[mt][t][r] - mn);
                    QPs[prow][((t ^ (quad >> 1)) * 16) + lnx] = f2bf(pe);
                }
            }
            #pragma unroll
            for (int t = 0; t < 4; ++t)
                #pragma unroll
                for (int r = 0; r < 4; ++r)
                    acc_o[mt][t][r] *= alpha[r];
            #pragma unroll
            for (int r = 0; r < 4; ++r) acc_l[mt][r] *= alpha[r];
        }

        // O += P @ V ; l += P @ 1. pf unswizzle: phys = quad ^ ((ln>>2)&3)
        #pragma unroll
        for (int s = 0; s < 2; ++s) {
            bf16x8 pf[2];
            #pragma unroll
            for (int mt = 0; mt < 2; ++mt)
                pf[mt] = *(const bf16x8*)(&QPs[wave * 32 + mt * 16 + ln]
                                             [s * 32 + ((quad ^ ((ln >> 2) & 3)) * 8)]);
            #pragma unroll
            for (int t = 0; t < 4; ++t) {
                bf16x8 vf = *(const bf16x8*)(&Vs[t * 16 + ln][s * 32 + quad * 8]);
                #pragma unroll
                for (int mt = 0; mt < 2; ++mt)
                    acc_o[mt][t] = __builtin_amdgcn_mfma_f32_16x16x32_bf16(
                        pf[mt], vf, acc_o[mt][t], 0, 0, 0);
            }
            #pragma unroll
            for (int mt = 0; mt < 2; ++mt)
                acc_l[mt] = __builtin_amdgcn_mfma_f32_16x16x32_bf16(
                    pf[mt], ones8, acc_l[mt], 0, 0, 0);
        }
    }

    // epilogue: normalize, write [B,S,H*64+dk]
    const int b = bh >> 4, hh = bh & (NUM_HEADS - 1);
    #pragma unroll
    for (int mt = 0; mt < 2; ++mt)
        #pragma unroll
        for (int r = 0; r < 4; ++r) {
            float inv = 1.0f / acc_l[mt][r];
            int i = q0 + wave * 32 + mt * 16 + quad * 4 + r;
            size_t rowoff = ((size_t)(b * SEQ + i)) * D_MODEL + hh * D_K;
            #pragma unroll
            for (int t = 0; t < 4; ++t)
                attn[rowoff + t * 16 + ln] = f2bf(acc_o[mt][t][r] * inv);
        }
}

extern "C" void kernel_launch(void* const* d_in, const int* in_sizes, int n_in,
                              void* d_out, int out_size, void* d_ws, size_t ws_size,
                              hipStream_t stream)
{
    const void* x     = d_in[0];
    // d_in[1] = int32 tril mask -- causal handled analytically
    const void* w_qkv = d_in[2];
    const void* b_qkv = d_in[3];
    const void* w_out = d_in[4];
    const void* b_out = d_in[5];

    char* ws = (char*)d_ws;
    int*    flag   = (int*)ws;                  size_t off = 256;
    ushort* WqkvT  = (ushort*)(ws + off);       off += (size_t)3 * D_MODEL * D_MODEL * 2;
    ushort* WoutT  = (ushort*)(ws + off);       off += (size_t)D_MODEL * D_MODEL * 2;
    ushort* bq     = (ushort*)(ws + off);       off += 8192;
    ushort* bo     = (ushort*)(ws + off);       off += 8192;
    ushort* qkv_ws = (ushort*)(ws + off);       off += (size_t)3 * BATCH * NUM_HEADS * SEQ * D_K * 2;
    ushort* xb     = (ushort*)(ws + off);       // aliases attn_ws: xb dead after QKV gemm
    ushort* attn_ws = xb;

    const int M = BATCH * SEQ;          // 4096
    const size_t per = (size_t)BATCH * NUM_HEADS * SEQ * D_K;

    detect_f32<<<1, 64, 0, stream>>>((const ushort*)x, flag);

    const int nx = M * D_MODEL;
    convert_bf16<<<nx / 8 / 256, 256, 0, stream>>>(x, xb, nx, flag);
    convert_bf16<<<2, 256, 0, stream>>>(b_qkv, bq, 3 * D_MODEL, flag);
    convert_bf16<<<1, 256, 0, stream>>>(b_out, bo, D_MODEL, flag);
    transpose_w<<<dim3(3 * D_MODEL / 64, D_MODEL / 64), 256, 0, stream>>>(
        w_qkv, WqkvT, D_MODEL, 3 * D_MODEL, flag);
    transpose_w<<<dim3(D_MODEL / 64, D_MODEL / 64), 256, 0, stream>>>(
        w_out, WoutT, D_MODEL, D_MODEL, flag);

    gemm128<1><<<dim3(3 * D_MODEL / 128, M / 128), 256, 0, stream>>>(
        xb, WqkvT, bq, qkv_ws, 3 * D_MODEL, D_MODEL, flag);

    dim3 ga(SEQ / 64, BATCH * NUM_HEADS);
    flash_attn2<<<ga, 128, 0, stream>>>(qkv_ws, qkv_ws + per, qkv_ws + 2 * per, attn_ws);

    gemm128<0><<<dim3(D_MODEL / 128, M / 128), 256, 0, stream>>>(
        attn_ws, WoutT, bo, d_out, D_MODEL, D_MODEL, flag);
}